// Round 6
// baseline (159.266 us; speedup 1.0000x reference)
//
#include <hip/hip_runtime.h>
#include <hip/hip_bf16.h>
#include <stdint.h>

#define NEG_INF -9.0e15f
#define LRELU_ALPHA 0.2f
#define LOG2E 1.442695040888963f

using bf16x8  = __attribute__((ext_vector_type(8))) short;
using f32x4   = __attribute__((ext_vector_type(4))) float;
using short4v = __attribute__((ext_vector_type(4))) short;
using int4v   = __attribute__((ext_vector_type(4))) int;
using float4v = __attribute__((ext_vector_type(4))) float;
using uint4v  = __attribute__((ext_vector_type(4))) unsigned;

static __device__ __forceinline__ float b2f(short s) {
  unsigned u = ((unsigned)(unsigned short)s) << 16;
  return __builtin_bit_cast(float, u);
}
static __device__ __forceinline__ short f2bf(float f) {
  unsigned u = __builtin_bit_cast(unsigned, f);
  u = u + 0x7FFFu + ((u >> 16) & 1u);   // RNE
  return (short)(u >> 16);
}
// pack two f32 -> one dword of 2 bf16 (RNE), gfx950 v_cvt_pk_bf16_f32
static __device__ __forceinline__ unsigned cvtpk_bf16(float lo, float hi) {
  unsigned r;
  asm volatile("v_cvt_pk_bf16_f32 %0, %1, %2" : "=v"(r) : "v"(lo), "v"(hi));
  return r;
}
static __device__ __forceinline__ void gload16(const void* g, void* l) {
  __builtin_amdgcn_global_load_lds((const __attribute__((address_space(1))) void*)g,
                                   (__attribute__((address_space(3))) void*)l, 16, 0, 0);
}

// ---------------- f32 -> bf16 cast (8 elems/thread), sanitizing ----------------
__global__ __launch_bounds__(256) void cast_f32_bf16_kernel(
    const float* __restrict__ src, short* __restrict__ dst, int n)
{
  int i0 = (blockIdx.x * 256 + threadIdx.x) * 8;
  if (i0 >= n) return;
  float4v v0 = *(const float4v*)(src + i0);
  float4v v1 = *(const float4v*)(src + i0 + 4);
  short os[8] __attribute__((aligned(16)));
#pragma unroll
  for (int k = 0; k < 8; ++k) {
    float x = (k < 4) ? v0[k] : v1[k - 4];
    x = (x - x == 0.0f) ? x : 0.0f;
    os[k] = f2bf(x);
  }
  *(int4v*)(dst + i0) = *(const int4v*)os;
}

// ---------------- W (f32, 256x256) -> W^T (bf16) in one pass ----------------
__global__ __launch_bounds__(256) void castT_W_kernel(
    const float* __restrict__ src, short* __restrict__ dst)
{
  __shared__ float t[64][65];
  const int m0 = blockIdx.x * 64, n0 = blockIdx.y * 64;
  const int tid = threadIdx.x;
  const int rr = tid >> 3, cc = (tid & 7) * 8;
#pragma unroll
  for (int p = 0; p < 2; ++p) {
    int row = rr + p * 32;
    const float* sp = src + (m0 + row) * 256 + n0 + cc;
    float4v v0 = *(const float4v*)sp;
    float4v v1 = *(const float4v*)(sp + 4);
#pragma unroll
    for (int j = 0; j < 4; ++j) { t[row][cc + j] = v0[j]; t[row][cc + 4 + j] = v1[j]; }
  }
  __syncthreads();
#pragma unroll
  for (int p = 0; p < 2; ++p) {
    int orow = rr + p * 32;
    short vv[8] __attribute__((aligned(16)));
#pragma unroll
    for (int j = 0; j < 8; ++j) vv[j] = f2bf(t[cc + j][orow]);
    short* dp = dst + (n0 + orow) * 256 + m0 + cc;
    *(int4v*)dp = *(const int4v*)vv;
  }
}

// ---------------- transpose (bf16), 64x64 LDS tiles (for Wh -> Wh_t) ----------------
__global__ __launch_bounds__(256) void transpose_bf16_kernel(
    const short* __restrict__ src, short* __restrict__ dst,
    int M, int N, long long ss, long long ds)
{
  __shared__ short t[64][68];
  const int b = blockIdx.z;
  src += (long long)b * ss; dst += (long long)b * ds;
  const int m0 = blockIdx.x * 64, n0 = blockIdx.y * 64;
  const int tid = threadIdx.x;
  const int rr = tid >> 3, cc = (tid & 7) * 8;
#pragma unroll
  for (int p = 0; p < 2; ++p) {
    int row = rr + p * 32;
    const short* sp = src + (long long)(m0 + row) * N + n0 + cc;
    short4v v0 = *(const short4v*)sp;
    short4v v1 = *(const short4v*)(sp + 4);
    *(short4v*)&t[row][cc]     = v0;
    *(short4v*)&t[row][cc + 4] = v1;
  }
  __syncthreads();
#pragma unroll
  for (int p = 0; p < 2; ++p) {
    int orow = rr + p * 32;
    short vv[8] __attribute__((aligned(16)));
#pragma unroll
    for (int j = 0; j < 8; ++j) vv[j] = t[cc + j][orow];
    short* dp = dst + (long long)(n0 + orow) * M + m0 + cc;
    *(int4v*)dp = *(const int4v*)vv;
  }
}

// ---------------- e1/e2 = Wh @ a1/a2 (one wave per row); a is f32 ----------------
__global__ __launch_bounds__(256) void evec_kernel(
    const short* __restrict__ Wh, const float* __restrict__ a,
    float* __restrict__ e1, float* __restrict__ e2)
{
  const int wid = threadIdx.x >> 6, lane = threadIdx.x & 63;
  const long long r = (long long)blockIdx.x * 4 + wid;
  short4v hv   = *(const short4v*)(Wh + r * 256 + lane * 4);
  float4v a1v  = *(const float4v*)(a + lane * 4);
  float4v a2v  = *(const float4v*)(a + 256 + lane * 4);
  float s1 = 0.f, s2 = 0.f;
#pragma unroll
  for (int k = 0; k < 4; ++k) {
    float x = b2f(hv[k]);
    s1 += x * a1v[k];
    s2 += x * a2v[k];
  }
#pragma unroll
  for (int off = 32; off > 0; off >>= 1) {
    s1 += __shfl_xor(s1, off, 64);
    s2 += __shfl_xor(s2, off, 64);
  }
  if (lane == 0) { e1[r] = s1; e2[r] = s2; }
}

// ------------- pass 1: adj -> bitmask (1 byte per 8 cols) + per-row softmax consts -------------
// P[i,j] = bit ? exp2(lrelu(e1_i+e2_j)*L_i + D_i) : 0,  L=log2e, D=-M*log2e-log2(S).
// Empty row (no neighbors): reference softmax is uniform 1/2048 -> L=0, D=-11, mask=0xFF.
__global__ __launch_bounds__(256) void pack_stats_kernel(
    const int* __restrict__ adj, const float* __restrict__ e1,
    const float* __restrict__ e2, unsigned char* __restrict__ mask,
    float* __restrict__ Lr, float* __restrict__ Dr)
{
  const int i = blockIdx.x;
  const int b = blockIdx.y;
  const long long row = (long long)b * 2048 + i;
  const int tid = threadIdx.x;
  const int wid = tid >> 6, lane = tid & 63;
  const int j0 = tid * 8;

  const int*   arow = adj + row * 2048 + j0;
  const float  ei   = e1[row];
  const float* e2b  = e2 + b * 2048 + j0;

  int4v   a0 = *(const int4v*)(arow);
  int4v   a1 = *(const int4v*)(arow + 4);
  float4v f0 = *(const float4v*)(e2b);
  float4v f1 = *(const float4v*)(e2b + 4);

  float s[8]; unsigned byte = 0u;
#pragma unroll
  for (int k = 0; k < 8; ++k) {
    float x = ei + (k < 4 ? f0[k] : f1[k - 4]);
    float v = fmaxf(x, LRELU_ALPHA * x);
    int  ad = (k < 4 ? a0[k] : a1[k - 4]);
    if (ad > 0) { s[k] = v; byte |= (1u << k); } else s[k] = NEG_INF;
  }
  float m = s[0];
#pragma unroll
  for (int k = 1; k < 8; ++k) m = fmaxf(m, s[k]);
#pragma unroll
  for (int off = 32; off > 0; off >>= 1) m = fmaxf(m, __shfl_xor(m, off, 64));

  __shared__ float wmax[4], wsum[4];
  if (lane == 0) wmax[wid] = m;
  __syncthreads();
  const float M = fmaxf(fmaxf(wmax[0], wmax[1]), fmaxf(wmax[2], wmax[3]));
  const bool empty = (M == NEG_INF);

  mask[row * 256 + tid] = empty ? (unsigned char)0xFF : (unsigned char)byte;

  float t = 0.f;
#pragma unroll
  for (int k = 0; k < 8; ++k) t += __expf(s[k] - M);   // non-edge: exp(-9e15)=0; empty row: exp(0)=1
#pragma unroll
  for (int off = 32; off > 0; off >>= 1) t += __shfl_xor(t, off, 64);
  if (lane == 0) wsum[wid] = t;
  __syncthreads();
  if (tid == 0) {
    const float S = wsum[0] + wsum[1] + wsum[2] + wsum[3];
    Lr[row] = empty ? 0.0f : LOG2E;
    Dr[row] = empty ? -11.0f : (-M * LOG2E - __log2f(S));
  }
}

// ------------- pass 2: fused P-recompute + attention write + P@Wh + ELU -------------
// Block = 32 rows x 256 out-cols, 4 waves (wave w -> cols w*64..+63). No LDS, no barriers.
// All waves compute identical P fragments (needed as their MFMA A operand);
// wave 0 additionally writes the f32 attention. B (Wh_t) from L2 (XCD-pinned: bz=bid&7).
__global__ __launch_bounds__(256, 2) void fused_pv_kernel(
    const unsigned char* __restrict__ mask, const float* __restrict__ e1,
    const float* __restrict__ e2, const float* __restrict__ Lr,
    const float* __restrict__ Dr, const short* __restrict__ Bt,
    float* __restrict__ attnw, float* __restrict__ C)
{
  const int bid = blockIdx.x;
  const int bz  = bid & 7;
  const int M0  = (bid >> 3) << 5;          // 64 m-tiles of 32 rows per batch
  const int tid = threadIdx.x;
  const int w = tid >> 6, lane = tid & 63;
  const int g = lane >> 4, lr = lane & 15;

  const long long rb = (long long)bz * 2048;
  const int r0 = M0 + lr, r1 = M0 + 16 + lr;
  const float E1_0 = e1[rb + r0], L0 = Lr[rb + r0], D0 = Dr[rb + r0];
  const float E1_1 = e1[rb + r1], L1 = Lr[rb + r1], D1 = Dr[rb + r1];
  const unsigned long long* mrow0 = (const unsigned long long*)(mask + (rb + r0) * 256);
  const unsigned long long* mrow1 = (const unsigned long long*)(mask + (rb + r1) * 256);
  const float* e2b = e2 + rb;
  Bt    += (long long)bz * 524288;
  attnw += (long long)bz * 4194304;
  C     += (long long)bz * 524288;

  f32x4 acc[2][4] = {};

  for (int k0 = 0; k0 < 2048; k0 += 64) {
    const unsigned long long mw0 = mrow0[k0 >> 6];
    const unsigned long long mw1 = mrow1[k0 >> 6];
    bf16x8 af[2][2];
#pragma unroll
    for (int s = 0; s < 2; ++s) {
      const int kc = s * 4 + g;             // 8-elem chunk 0..7 within the 64-k tile
      const int kk = k0 + kc * 8;
      const float4v eo = *(const float4v*)(e2b + kk);
      const float4v eh = *(const float4v*)(e2b + kk + 4);
#pragma unroll
      for (int i = 0; i < 2; ++i) {
        const float E1v = i ? E1_1 : E1_0;
        const float Lv  = i ? L1 : L0;
        const float Dv  = i ? D1 : D0;
        const unsigned by = (unsigned)((i ? mw1 : mw0) >> (kc * 8)) & 0xFFu;
        float p[8];
#pragma unroll
        for (int e = 0; e < 8; ++e) {
          float x = E1v + (e < 4 ? eo[e] : eh[e - 4]);
          float v = fmaxf(x, LRELU_ALPHA * x);
          float P = __builtin_amdgcn_exp2f(fmaf(v, Lv, Dv));
          p[e] = ((by >> e) & 1u) ? P : 0.0f;
        }
        if (w == 0) {
          float4v o0, o1;
#pragma unroll
          for (int e = 0; e < 4; ++e) { o0[e] = p[e]; o1[e] = p[e + 4]; }
          float* op = attnw + (long long)(i ? r1 : r0) * 2048 + kk;
          *(float4v*)op       = o0;
          *(float4v*)(op + 4) = o1;
        }
        uint4v uv;
        uv[0] = cvtpk_bf16(p[0], p[1]);
        uv[1] = cvtpk_bf16(p[2], p[3]);
        uv[2] = cvtpk_bf16(p[4], p[5]);
        uv[3] = cvtpk_bf16(p[6], p[7]);
        af[i][s] = __builtin_bit_cast(bf16x8, uv);
      }
    }
#pragma unroll
    for (int s = 0; s < 2; ++s)
#pragma unroll
      for (int j = 0; j < 4; ++j) {
        bf16x8 bv = *(const bf16x8*)(Bt + (long long)(w * 64 + j * 16 + lr) * 2048
                                        + k0 + (s * 4 + g) * 8);
#pragma unroll
        for (int i = 0; i < 2; ++i)
          acc[i][j] = __builtin_amdgcn_mfma_f32_16x16x32_bf16(af[i][s], bv, acc[i][j], 0, 0, 0);
      }
  }

  // C/D: col=lane&15, row=(lane>>4)*4+reg  [m89]
#pragma unroll
  for (int i = 0; i < 2; ++i) {
    int row_base = M0 + i * 16 + 4 * g;
#pragma unroll
    for (int j = 0; j < 4; ++j) {
      int col = w * 64 + j * 16 + lr;
#pragma unroll
      for (int r = 0; r < 4; ++r) {
        float v = acc[i][j][r];
        v = (v > 0.f) ? v : (__expf(v) - 1.f);   // ELU
        C[(long long)(row_base + r) * 256 + col] = v;
      }
    }
  }
}

// ------------- bf16 MFMA GEMM (m97 structure), used for Wh = h @ W -------------
__global__ __launch_bounds__(256) void gemm_bt(
    const short* __restrict__ A, const short* __restrict__ Bt,
    short* __restrict__ C, int N, int K)
{
  __shared__ short As[128 * 32];
  __shared__ short Bs[128 * 32];
  const int m0 = blockIdx.x * 128, n0 = blockIdx.y * 128;
  const int tid = threadIdx.x;
  const int w = tid >> 6, lane = tid & 63;
  const int wr = w >> 1, wc = w & 1;
  const int g = lane >> 4, lr = lane & 15;

  f32x4 acc[4][4] = {};

  for (int k0 = 0; k0 < K; k0 += 32) {
    __syncthreads();
#pragma unroll
    for (int q = 0; q < 2; ++q) {
      int p = w * 2 + q;
      int c = p * 64 + lane;
      int row = c >> 2, kq = (c & 3) << 3;
      gload16(A  + (long long)(m0 + row) * K + k0 + kq, As + p * 512);
      gload16(Bt + (long long)(n0 + row) * K + k0 + kq, Bs + p * 512);
    }
    __syncthreads();

    bf16x8 af[4], bfr[4];
#pragma unroll
    for (int i = 0; i < 4; ++i) {
      af[i]  = *(const bf16x8*)(As + (wr * 64 + i * 16 + lr) * 32 + 8 * g);
      bfr[i] = *(const bf16x8*)(Bs + (wc * 64 + i * 16 + lr) * 32 + 8 * g);
    }
#pragma unroll
    for (int i = 0; i < 4; ++i)
#pragma unroll
      for (int j = 0; j < 4; ++j)
        acc[i][j] = __builtin_amdgcn_mfma_f32_16x16x32_bf16(af[i], bfr[j], acc[i][j], 0, 0, 0);
  }

#pragma unroll
  for (int i = 0; i < 4; ++i) {
    int row_base = m0 + wr * 64 + i * 16 + 4 * g;
#pragma unroll
    for (int j = 0; j < 4; ++j) {
      int col = n0 + wc * 64 + j * 16 + lr;
#pragma unroll
      for (int r = 0; r < 4; ++r)
        C[(long long)(row_base + r) * N + col] = f2bf(acc[i][j][r]);
    }
  }
}

extern "C" void kernel_launch(void* const* d_in, const int* in_sizes, int n_in,
                              void* d_out, int out_size, void* d_ws, size_t ws_size,
                              hipStream_t stream)
{
  const float* h   = (const float*)d_in[0];   // (8,2048,256) f32
  const int*   adj = (const int*)d_in[1];     // (8,2048,2048) int32
  const float* W   = (const float*)d_in[2];   // (256,256) f32
  const float* a   = (const float*)d_in[3];   // (512,1) f32

  float* hp_out   = (float*)d_out;            // elu(h_prime): 4,194,304 f32
  float* attn_out = hp_out + 4194304LL;       // attention: 33,554,432 f32

  // workspace: 25,559,040 B (same total as the passing round-5 layout).
  // mask reuses the h_bf region (h_bf is dead after gemm_bt; pack_stats runs later).
  short* h_bf = (short*)d_ws;                 // 16384x256 bf16 (8.39 MB)
  unsigned char* mask = (unsigned char*)d_ws; // 8*2048*256 = 4.19 MB, overlays h_bf
  short* W_t  = h_bf + 4194304;               // 256x256 bf16
  short* Wh   = W_t + 65536;                  // 16384x256 bf16
  short* Wh_t = Wh + 4194304;                 // 8 x (256x2048) bf16
  float* e1   = (float*)(Wh_t + 4194304);     // 16384
  float* e2   = e1 + 16384;                   // 16384
  float* Lr   = e2 + 16384;                   // 16384
  float* Dr   = Lr + 16384;                   // 16384

  // 1) h f32 -> bf16
  cast_f32_bf16_kernel<<<2048, 256, 0, stream>>>(h, h_bf, 4194304);
  // 2) W f32 -> W^T bf16 (one pass)
  castT_W_kernel<<<dim3(4, 4), 256, 0, stream>>>(W, W_t);
  // 3) Wh = h @ W (bf16)
  gemm_bt<<<dim3(128, 2, 1), 256, 0, stream>>>(h_bf, W_t, Wh, 256, 256);
  // 4) Wh^T per batch (2048x256 -> 256x2048)
  transpose_bf16_kernel<<<dim3(32, 4, 8), 256, 0, stream>>>(Wh, Wh_t, 2048, 256, 524288LL, 524288LL);
  // 5) e1/e2
  evec_kernel<<<4096, 256, 0, stream>>>(Wh, a, e1, e2);
  // 6) adj -> bitmask + per-row (L,D)   [h_bf is dead; mask overlays it]
  pack_stats_kernel<<<dim3(2048, 8), 256, 0, stream>>>(adj, e1, e2, mask, Lr, Dr);
  // 7) fused: recompute P, write attention, P @ Wh with ELU
  fused_pv_kernel<<<512, 256, 0, stream>>>(mask, e1, e2, Lr, Dr, Wh_t, attn_out, hp_out);
}

// Round 7
// 125.012 us; speedup vs baseline: 1.2740x; 1.2740x over previous
//
#include <hip/hip_runtime.h>
#include <hip/hip_bf16.h>
#include <stdint.h>

#define NEG_INF -9.0e15f
#define LRELU_ALPHA 0.2f
#define LOG2E 1.442695040888963f

using bf16x8  = __attribute__((ext_vector_type(8))) short;
using f32x4   = __attribute__((ext_vector_type(4))) float;
using short4v = __attribute__((ext_vector_type(4))) short;
using int4v   = __attribute__((ext_vector_type(4))) int;
using float4v = __attribute__((ext_vector_type(4))) float;
using uint4v  = __attribute__((ext_vector_type(4))) unsigned;

static __device__ __forceinline__ float b2f(short s) {
  unsigned u = ((unsigned)(unsigned short)s) << 16;
  return __builtin_bit_cast(float, u);
}
static __device__ __forceinline__ short f2bf(float f) {
  unsigned u = __builtin_bit_cast(unsigned, f);
  u = u + 0x7FFFu + ((u >> 16) & 1u);   // RNE
  return (short)(u >> 16);
}
// pack two f32 -> one dword of 2 bf16 (RNE), gfx950 v_cvt_pk_bf16_f32
static __device__ __forceinline__ unsigned cvtpk_bf16(float lo, float hi) {
  unsigned r;
  asm volatile("v_cvt_pk_bf16_f32 %0, %1, %2" : "=v"(r) : "v"(lo), "v"(hi));
  return r;
}
static __device__ __forceinline__ void gload16(const void* g, void* l) {
  __builtin_amdgcn_global_load_lds((const __attribute__((address_space(1))) void*)g,
                                   (__attribute__((address_space(3))) void*)l, 16, 0, 0);
}

// ---------------- W (f32, 256x256) -> W^T (bf16) in one pass ----------------
__global__ __launch_bounds__(256) void castT_W_kernel(
    const float* __restrict__ src, short* __restrict__ dst)
{
  __shared__ float t[64][65];
  const int m0 = blockIdx.x * 64, n0 = blockIdx.y * 64;
  const int tid = threadIdx.x;
  const int rr = tid >> 3, cc = (tid & 7) * 8;
#pragma unroll
  for (int p = 0; p < 2; ++p) {
    int row = rr + p * 32;
    const float* sp = src + (m0 + row) * 256 + n0 + cc;
    float4v v0 = *(const float4v*)sp;
    float4v v1 = *(const float4v*)(sp + 4);
#pragma unroll
    for (int j = 0; j < 4; ++j) { t[row][cc + j] = v0[j]; t[row][cc + 4 + j] = v1[j]; }
  }
  __syncthreads();
#pragma unroll
  for (int p = 0; p < 2; ++p) {
    int orow = rr + p * 32;
    short vv[8] __attribute__((aligned(16)));
#pragma unroll
    for (int j = 0; j < 8; ++j) vv[j] = f2bf(t[cc + j][orow]);
    short* dp = dst + (n0 + orow) * 256 + m0 + cc;
    *(int4v*)dp = *(const int4v*)vv;
  }
}

// ---------------- transpose (bf16), 64x64 LDS tiles (for Wh -> Wh_t) ----------------
__global__ __launch_bounds__(256) void transpose_bf16_kernel(
    const short* __restrict__ src, short* __restrict__ dst,
    int M, int N, long long ss, long long ds)
{
  __shared__ short t[64][68];
  const int b = blockIdx.z;
  src += (long long)b * ss; dst += (long long)b * ds;
  const int m0 = blockIdx.x * 64, n0 = blockIdx.y * 64;
  const int tid = threadIdx.x;
  const int rr = tid >> 3, cc = (tid & 7) * 8;
#pragma unroll
  for (int p = 0; p < 2; ++p) {
    int row = rr + p * 32;
    const short* sp = src + (long long)(m0 + row) * N + n0 + cc;
    short4v v0 = *(const short4v*)sp;
    short4v v1 = *(const short4v*)(sp + 4);
    *(short4v*)&t[row][cc]     = v0;
    *(short4v*)&t[row][cc + 4] = v1;
  }
  __syncthreads();
#pragma unroll
  for (int p = 0; p < 2; ++p) {
    int orow = rr + p * 32;
    short vv[8] __attribute__((aligned(16)));
#pragma unroll
    for (int j = 0; j < 8; ++j) vv[j] = t[cc + j][orow];
    short* dp = dst + (long long)(n0 + orow) * M + m0 + cc;
    *(int4v*)dp = *(const int4v*)vv;
  }
}

// ---------------- e1/e2 = Wh @ a1/a2 (one wave per row); a is f32 ----------------
__global__ __launch_bounds__(256) void evec_kernel(
    const short* __restrict__ Wh, const float* __restrict__ a,
    float* __restrict__ e1, float* __restrict__ e2)
{
  const int wid = threadIdx.x >> 6, lane = threadIdx.x & 63;
  const long long r = (long long)blockIdx.x * 4 + wid;
  short4v hv   = *(const short4v*)(Wh + r * 256 + lane * 4);
  float4v a1v  = *(const float4v*)(a + lane * 4);
  float4v a2v  = *(const float4v*)(a + 256 + lane * 4);
  float s1 = 0.f, s2 = 0.f;
#pragma unroll
  for (int k = 0; k < 4; ++k) {
    float x = b2f(hv[k]);
    s1 += x * a1v[k];
    s2 += x * a2v[k];
  }
#pragma unroll
  for (int off = 32; off > 0; off >>= 1) {
    s1 += __shfl_xor(s1, off, 64);
    s2 += __shfl_xor(s2, off, 64);
  }
  if (lane == 0) { e1[r] = s1; e2[r] = s2; }
}

// ------------- pass 1: adj -> bitmask + per-row softmax consts (verified round 6) -------------
// P[i,j] = bit ? exp2(lrelu(e1_i+e2_j)*L_i + D_i) : 0,  L=log2e, D=-M*log2e-log2(S).
// Empty row: reference softmax is uniform 1/2048 -> L=0, D=-11, mask=0xFF.
__global__ __launch_bounds__(256) void pack_stats_kernel(
    const int* __restrict__ adj, const float* __restrict__ e1,
    const float* __restrict__ e2, unsigned char* __restrict__ mask,
    float* __restrict__ Lr, float* __restrict__ Dr)
{
  const int i = blockIdx.x;
  const int b = blockIdx.y;
  const long long row = (long long)b * 2048 + i;
  const int tid = threadIdx.x;
  const int wid = tid >> 6, lane = tid & 63;
  const int j0 = tid * 8;

  const int*   arow = adj + row * 2048 + j0;
  const float  ei   = e1[row];
  const float* e2b  = e2 + b * 2048 + j0;

  int4v   a0 = *(const int4v*)(arow);
  int4v   a1 = *(const int4v*)(arow + 4);
  float4v f0 = *(const float4v*)(e2b);
  float4v f1 = *(const float4v*)(e2b + 4);

  float s[8]; unsigned byte = 0u;
#pragma unroll
  for (int k = 0; k < 8; ++k) {
    float x = ei + (k < 4 ? f0[k] : f1[k - 4]);
    float v = fmaxf(x, LRELU_ALPHA * x);
    int  ad = (k < 4 ? a0[k] : a1[k - 4]);
    if (ad > 0) { s[k] = v; byte |= (1u << k); } else s[k] = NEG_INF;
  }
  float m = s[0];
#pragma unroll
  for (int k = 1; k < 8; ++k) m = fmaxf(m, s[k]);
#pragma unroll
  for (int off = 32; off > 0; off >>= 1) m = fmaxf(m, __shfl_xor(m, off, 64));

  __shared__ float wmax[4], wsum[4];
  if (lane == 0) wmax[wid] = m;
  __syncthreads();
  const float M = fmaxf(fmaxf(wmax[0], wmax[1]), fmaxf(wmax[2], wmax[3]));
  const bool empty = (M == NEG_INF);

  mask[row * 256 + tid] = empty ? (unsigned char)0xFF : (unsigned char)byte;

  float t = 0.f;
#pragma unroll
  for (int k = 0; k < 8; ++k) t += __expf(s[k] - M);
#pragma unroll
  for (int off = 32; off > 0; off >>= 1) t += __shfl_xor(t, off, 64);
  if (lane == 0) wsum[wid] = t;
  __syncthreads();
  if (tid == 0) {
    const float S = wsum[0] + wsum[1] + wsum[2] + wsum[3];
    Lr[row] = empty ? 0.0f : LOG2E;
    Dr[row] = empty ? -11.0f : (-M * LOG2E - __log2f(S));
  }
}

// ------------- pass 2 (FIXED): round-5 gemm_attn skeleton with cooperative P-stage -------------
// Block = 32 rows x 256 cols, BK=64, 4 waves. LDS: As (P as bf16, swizzled) + Bs (Wh_t).
// P-stage: thread (pr=tid>>3, kc8=tid&7) computes 8 P values once, writes f32 attn
// (coalesced 32B/lane) and bf16x8 into As at chunk (kc8 ^ (pr&7)) [2-way read banks].
// B-stage: identical to verified round-5 (global_load_lds, chunk ^ (col&7)).
__global__ __launch_bounds__(256, 2) void fused_pv_kernel(
    const unsigned char* __restrict__ mask, const float* __restrict__ e1,
    const float* __restrict__ e2, const float* __restrict__ Lr,
    const float* __restrict__ Dr, const short* __restrict__ Bt,
    float* __restrict__ attnw, float* __restrict__ C)
{
  __shared__ short As[32 * 64];     // 4 KB
  __shared__ short Bs[256 * 64];    // 32 KB
  const int bid = blockIdx.x;
  const int bz  = bid & 7;          // XCD-pinned batch
  const int M0  = (bid >> 3) << 5;
  const int tid = threadIdx.x;
  const int w = tid >> 6, lane = tid & 63;
  const int g = lane >> 4, lr = lane & 15;

  const long long rb = (long long)bz * 2048;
  Bt    += (long long)bz * 524288;
  attnw += (long long)bz * 4194304;
  C     += (long long)bz * 524288;

  // P-stage identities
  const int pr = tid >> 3, kc8 = tid & 7;
  const int prow = M0 + pr;
  const float E1p = e1[rb + prow];
  const float Lp  = Lr[rb + prow];
  const float Dp  = Dr[rb + prow];
  const unsigned char* mrow = mask + (rb + prow) * 256;
  float* arow = attnw + (long long)prow * 2048;
  short* as_wr = As + pr * 64 + ((kc8 ^ (pr & 7)) << 3);
  const float* e2b = e2 + rb;

  // B-stage identities (round-5 verbatim)
  const int bcol_off = lane >> 3;
  const int bchunk   = (lane & 7) ^ ((lane >> 3) & 7);

  f32x4 acc[2][4] = {};

  for (int k0 = 0; k0 < 2048; k0 += 64) {
    __syncthreads();                       // prev-iter LDS reads done
    // --- P-stage: 8 values/thread, once ---
    {
      const unsigned by = mrow[(k0 >> 3) + kc8];
      const int kk = k0 + kc8 * 8;
      float4v eo = *(const float4v*)(e2b + kk);
      float4v eh = *(const float4v*)(e2b + kk + 4);
      float p[8];
#pragma unroll
      for (int e = 0; e < 8; ++e) {
        float x = E1p + (e < 4 ? eo[e] : eh[e - 4]);
        float v = fmaxf(x, LRELU_ALPHA * x);
        float P = __builtin_amdgcn_exp2f(fmaf(v, Lp, Dp));
        p[e] = ((by >> e) & 1u) ? P : 0.0f;
      }
      float4v o0, o1;
#pragma unroll
      for (int e = 0; e < 4; ++e) { o0[e] = p[e]; o1[e] = p[e + 4]; }
      *(float4v*)(arow + kk)     = o0;     // attention output, written once
      *(float4v*)(arow + kk + 4) = o1;
      uint4v uv;
      uv[0] = cvtpk_bf16(p[0], p[1]);
      uv[1] = cvtpk_bf16(p[2], p[3]);
      uv[2] = cvtpk_bf16(p[4], p[5]);
      uv[3] = cvtpk_bf16(p[6], p[7]);
      *(bf16x8*)as_wr = __builtin_bit_cast(bf16x8, uv);
    }
    // --- B-stage: 256x64 bf16, 32 wave-issues of 1 KB (round-5 verbatim) ---
#pragma unroll
    for (int q = 0; q < 8; ++q) {
      int pp = w * 8 + q;
      int col = pp * 8 + bcol_off;
      gload16(Bt + (long long)col * 2048 + k0 + bchunk * 8, Bs + pp * 512);
    }
    __syncthreads();                       // drain ds_write (lgkm) + lds-DMA (vmcnt)

    bf16x8 af[2][2], bfr[4][2];
#pragma unroll
    for (int i = 0; i < 2; ++i) {
      int row = i * 16 + lr;
#pragma unroll
      for (int s = 0; s < 2; ++s)
        af[i][s] = *(const bf16x8*)(As + row * 64 + (((s * 4 + g) ^ (row & 7)) << 3));
    }
#pragma unroll
    for (int j = 0; j < 4; ++j) {
      int col = w * 64 + j * 16 + lr;
#pragma unroll
      for (int s = 0; s < 2; ++s)
        bfr[j][s] = *(const bf16x8*)(Bs + col * 64 + (((s * 4 + g) ^ (col & 7)) << 3));
    }
#pragma unroll
    for (int s = 0; s < 2; ++s)
#pragma unroll
      for (int i = 0; i < 2; ++i)
#pragma unroll
        for (int j = 0; j < 4; ++j)
          acc[i][j] = __builtin_amdgcn_mfma_f32_16x16x32_bf16(af[i][s], bfr[j][s], acc[i][j], 0, 0, 0);
  }

  // C/D: col=lane&15, row=(lane>>4)*4+reg  [m89]
#pragma unroll
  for (int i = 0; i < 2; ++i) {
    int row_base = M0 + i * 16 + 4 * g;
#pragma unroll
    for (int j = 0; j < 4; ++j) {
      int col = w * 64 + j * 16 + lr;
#pragma unroll
      for (int r = 0; r < 4; ++r) {
        float v = acc[i][j][r];
        v = (v > 0.f) ? v : (__expf(v) - 1.f);   // ELU
        C[(long long)(row_base + r) * 256 + col] = v;
      }
    }
  }
}

// ------------- Wh = cast(h_f32) @ W_t^T : m97 structure, A reg-staged f32->bf16 -------------
__global__ __launch_bounds__(256) void gemm_h_kernel(
    const float* __restrict__ A, const short* __restrict__ Bt,
    short* __restrict__ C, int N, int K)
{
  __shared__ short As[128 * 32];
  __shared__ short Bs[128 * 32];
  const int m0 = blockIdx.x * 128, n0 = blockIdx.y * 128;
  const int tid = threadIdx.x;
  const int w = tid >> 6, lane = tid & 63;
  const int wr = w >> 1, wc = w & 1;
  const int g = lane >> 4, lr = lane & 15;

  f32x4 acc[4][4] = {};

  for (int k0 = 0; k0 < K; k0 += 32) {
    __syncthreads();
    // stage A: 128x32 f32 -> bf16 via cvt_pk, 512 chunks, 2/thread
#pragma unroll
    for (int q = 0; q < 2; ++q) {
      int c = q * 256 + tid;
      int row = c >> 2, kq = (c & 3) << 3;
      const float* ap = A + (long long)(m0 + row) * K + k0 + kq;
      float4v u0 = *(const float4v*)ap;
      float4v u1 = *(const float4v*)(ap + 4);
      uint4v uv;
      uv[0] = cvtpk_bf16(u0[0], u0[1]);
      uv[1] = cvtpk_bf16(u0[2], u0[3]);
      uv[2] = cvtpk_bf16(u1[0], u1[1]);
      uv[3] = cvtpk_bf16(u1[2], u1[3]);
      *(bf16x8*)(As + c * 8) = __builtin_bit_cast(bf16x8, uv);
    }
    // stage B: bf16 via global_load_lds (m97 verbatim)
#pragma unroll
    for (int q = 0; q < 2; ++q) {
      int p = w * 2 + q;
      int c = p * 64 + lane;
      int row = c >> 2, kq = (c & 3) << 3;
      gload16(Bt + (long long)(n0 + row) * K + k0 + kq, Bs + p * 512);
    }
    __syncthreads();

    bf16x8 af[4], bfr[4];
#pragma unroll
    for (int i = 0; i < 4; ++i) {
      af[i]  = *(const bf16x8*)(As + (wr * 64 + i * 16 + lr) * 32 + 8 * g);
      bfr[i] = *(const bf16x8*)(Bs + (wc * 64 + i * 16 + lr) * 32 + 8 * g);
    }
#pragma unroll
    for (int i = 0; i < 4; ++i)
#pragma unroll
      for (int j = 0; j < 4; ++j)
        acc[i][j] = __builtin_amdgcn_mfma_f32_16x16x32_bf16(af[i], bfr[j], acc[i][j], 0, 0, 0);
  }

#pragma unroll
  for (int i = 0; i < 4; ++i) {
    int row_base = m0 + wr * 64 + i * 16 + 4 * g;
#pragma unroll
    for (int j = 0; j < 4; ++j) {
      int col = n0 + wc * 64 + j * 16 + lr;
#pragma unroll
      for (int r = 0; r < 4; ++r)
        C[(long long)(row_base + r) * N + col] = f2bf(acc[i][j][r]);
    }
  }
}

extern "C" void kernel_launch(void* const* d_in, const int* in_sizes, int n_in,
                              void* d_out, int out_size, void* d_ws, size_t ws_size,
                              hipStream_t stream)
{
  const float* h   = (const float*)d_in[0];   // (8,2048,256) f32
  const int*   adj = (const int*)d_in[1];     // (8,2048,2048) int32
  const float* W   = (const float*)d_in[2];   // (256,256) f32
  const float* a   = (const float*)d_in[3];   // (512,1) f32

  float* hp_out   = (float*)d_out;            // elu(h_prime): 4,194,304 f32
  float* attn_out = hp_out + 4194304LL;       // attention: 33,554,432 f32

  // workspace: 21.4 MB (< 25.56 MB proven-OK)
  unsigned char* mask = (unsigned char*)d_ws; // 8*2048*256 = 4.19 MB
  short* W_t  = (short*)(mask + 4194304);     // 256x256 bf16
  short* Wh   = W_t + 65536;                  // 16384x256 bf16
  short* Wh_t = Wh + 4194304;                 // 8 x (256x2048) bf16
  float* e1   = (float*)(Wh_t + 4194304);     // 16384
  float* e2   = e1 + 16384;                   // 16384
  float* Lr   = e2 + 16384;                   // 16384
  float* Dr   = Lr + 16384;                   // 16384

  // 1) W f32 -> W^T bf16
  castT_W_kernel<<<dim3(4, 4), 256, 0, stream>>>(W, W_t);
  // 2) Wh = cast(h) @ W (cast fused into A-staging)
  gemm_h_kernel<<<dim3(128, 2, 1), 256, 0, stream>>>(h, W_t, Wh, 256, 256);
  // 3) Wh^T per batch (2048x256 -> 256x2048)
  transpose_bf16_kernel<<<dim3(32, 4, 8), 256, 0, stream>>>(Wh, Wh_t, 2048, 256, 524288LL, 524288LL);
  // 4) e1/e2
  evec_kernel<<<4096, 256, 0, stream>>>(Wh, a, e1, e2);
  // 5) adj -> bitmask + per-row (L,D)
  pack_stats_kernel<<<dim3(2048, 8), 256, 0, stream>>>(adj, e1, e2, mask, Lr, Dr);
  // 6) fused: P recomputed once/block, attention written coalesced, P @ Wh + ELU
  fused_pv_kernel<<<512, 256, 0, stream>>>(mask, e1, e2, Lr, Dr, Wh_t, attn_out, hp_out);
}